// Round 10
// baseline (131.210 us; speedup 1.0000x reference)
//
#include <hip/hip_runtime.h>
#include <hip/hip_bf16.h>

#define BETA_LOG2E 14.426950408889634f   // 10 * log2(e)
#define EPSN 1e-6f

typedef __bf16 bf16x8 __attribute__((ext_vector_type(8)));
typedef float  f32x4  __attribute__((ext_vector_type(4)));

static __device__ inline unsigned short f2bf(float f) {
    __hip_bfloat16 h = __float2bfloat16(f);
    return __builtin_bit_cast(unsigned short, h);
}
static __device__ inline float bf2f(unsigned short u) {
    unsigned int b = ((unsigned int)u) << 16;
    return __builtin_bit_cast(float, b);
}

// ---------------------------------------------------------------------------
// Kernel 1 v4: L2-normalize over C, transpose [b][c][n] -> [b][n][c], bf16.
// v3 (4 blocks/CU) beat v2 (2/CU) ~15% -> HBM-latency bound; v4 doubles the
// concurrent miss chains again: 2048 blocks (8/CU), tile 16n x 256c.
// Numerics unchanged: raw->bf16 (pack), then scale->bf16 at writeout.
// ---------------------------------------------------------------------------
__global__ __launch_bounds__(256) void k_norm_transpose(
    const float* __restrict__ f0, const float* __restrict__ f1,
    unsigned short* __restrict__ aT, unsigned short* __restrict__ bT)
{
    __shared__ unsigned short tile[16 * 256];  // [n][c] raw bf16, 8 KB
    __shared__ float partial[64][16];          // [cg][n], 4 KB
    __shared__ float inv_l[16];

    int idx   = blockIdx.x;
    int which = idx >> 10;                 // 2048 = 2 x 4 x 256
    int rem   = idx & 1023;
    int b     = rem >> 8;
    int n0    = (rem & 255) * 16;
    const float* src = which ? f1 : f0;
    unsigned short* dst = which ? bT : aT;

    int t  = threadIdx.x;
    int nq = t & 3;     // 4 quads of 4 n  -> 16 n
    int cg = t >> 2;    // 64 groups of 4 c -> 256 c

    const float* sp = src + ((size_t)(b * 256 + cg * 4)) * 4096 + n0 + nq * 4;

    f32x4 ss = {0.f, 0.f, 0.f, 0.f};
    unsigned int pk[4][2];   // [j = n sub-row][2 uints = 4 bf16 over c]
#pragma unroll
    for (int i = 0; i < 4; ++i) {
        f32x4 v = *reinterpret_cast<const f32x4*>(sp + (size_t)i * 4096);
        ss += v * v;
#pragma unroll
        for (int j = 0; j < 4; ++j) {
            unsigned int h = f2bf(v[j]);
            if (i & 1) pk[j][i >> 1] |= h << 16;
            else       pk[j][i >> 1]  = h;
        }
    }
#pragma unroll
    for (int j = 0; j < 4; ++j) {
        int n = nq * 4 + j;
        *reinterpret_cast<uint2*>(&tile[n * 256 + cg * 4]) =
            *reinterpret_cast<const uint2*>(pk[j]);
    }
    *reinterpret_cast<f32x4*>(&partial[cg][nq * 4]) = ss;
    __syncthreads();
    if (t < 16) {
        float s = 0.f;
#pragma unroll
        for (int k = 0; k < 64; ++k) s += partial[k][t];
        inv_l[t] = 1.0f / fmaxf(sqrtf(s), EPSN);
    }
    __syncthreads();

    // write out: thread (n = t>>4, 16c chunk = t&15): 32 B contiguous;
    // wave covers 512B-per-n segments, fully coalesced.
    {
        int n  = t >> 4;
        int c0 = (t & 15) * 16;
        float inv = inv_l[n];
        uint4 v0 = *reinterpret_cast<const uint4*>(&tile[n * 256 + c0]);
        uint4 v1 = *reinterpret_cast<const uint4*>(&tile[n * 256 + c0 + 8]);
        unsigned int o[8];
#pragma unroll
        for (int k = 0; k < 4; ++k) {
            unsigned int u0 = (&v0.x)[k];
            unsigned int u1 = (&v1.x)[k];
            unsigned short a0 = f2bf(bf2f((unsigned short)(u0 & 0xffffu)) * inv);
            unsigned short a1 = f2bf(bf2f((unsigned short)(u0 >> 16)) * inv);
            unsigned short b0 = f2bf(bf2f((unsigned short)(u1 & 0xffffu)) * inv);
            unsigned short b1 = f2bf(bf2f((unsigned short)(u1 >> 16)) * inv);
            o[k]     = (unsigned int)a0 | ((unsigned int)a1 << 16);
            o[4 + k] = (unsigned int)b0 | ((unsigned int)b1 << 16);
        }
        size_t base = ((size_t)(b * 4096 + n0 + n)) * 256 + c0;
        *reinterpret_cast<uint4*>(&dst[base])     = *reinterpret_cast<const uint4*>(&o[0]);
        *reinterpret_cast<uint4*>(&dst[base + 8]) = *reinterpret_cast<const uint4*>(&o[4]);
    }
}

// ---------------------------------------------------------------------------
// Kernel 2 v11: round-8 winner (58.5us: DMA staging via global_load_lds,
// LDS dbuf 2x32KB, 1 barrier/chunk, XOR-swizzle) + register-neutral epilogue
// cuts (r2-validated numerics):
//  - Sy via Abel summation: U += Z per chunk; Sy = 16*(ks+1)*Z - U
//    (drops the per-score Sy FMA; U replaces Sy -> zero VGPR delta)
//  - pre-exp running max Sm (breaks exp2 dependency; exp2 once at writeout)
// stats[q][ks] = {Z, Sx, Sy, Pmax}; plain stores + separate finalize
// (cross-block fusion closed: 3 correctness failures r4/r6/r9).
// ---------------------------------------------------------------------------
__global__ __launch_bounds__(256) void k_flash(
    const unsigned short* __restrict__ aT, const unsigned short* __restrict__ bT,
    float* __restrict__ stats)
{
    __shared__ unsigned short kb[2 * 64 * 256];   // 64 KB double-buffered

    int idx   = blockIdx.x;
    int xcd   = idx & 7;                 // XCD swizzle: batch -> 2 XCDs
    int batch = xcd >> 1;
    int sub   = ((idx >> 3) << 1) | (xcd & 1);   // [0,128)
    int qt    = sub >> 2;                // [0,32)
    int ks    = sub & 3;                 // [0,4)

    int t    = threadIdx.x;
    int w    = t >> 6;
    int lane = t & 63;
    int quad = lane >> 4;
    int l15  = lane & 15;
    int q0w  = qt * 128 + w * 32;
    int k0   = ks * 1024;

    // resident A fragments: 2 strips of 16 queries x 8 K-steps
    bf16x8 afrag[2][8];
#pragma unroll
    for (int s = 0; s < 2; ++s) {
        const unsigned short* ap =
            aT + ((size_t)(batch * 4096 + q0w + s * 16 + l15)) * 256 + quad * 8;
#pragma unroll
        for (int kk = 0; kk < 8; ++kk)
            afrag[s][kk] = *reinterpret_cast<const bf16x8*>(ap + kk * 32);
    }

    // swizzled read offsets: logical blk = quad+4kk stored at blk^(key&7),
    // key&7 == l15&7 for the rows this lane reads
    int s7 = l15 & 7;
    int offs[8];
#pragma unroll
    for (int kk = 0; kk < 8; ++kk) offs[kk] = (((quad + 4 * kk) ^ s7) << 3);

    // staging: wave w, iter i covers key = i*8 + 2w + (lane>>5), block lane&31.
    // Source pre-swizzled: block' = (lane&31) ^ (key&7); key&7 = (2w+(lane>>5))&7.
    int krem = 2 * w + (lane >> 5);
    int goff = krem * 256 + (((lane & 31) ^ (krem & 7)) << 3);

    float Z[8], Sx[8], U[8], Sm[8];
#pragma unroll
    for (int i = 0; i < 8; ++i) { Z[i] = 0.f; Sx[i] = 0.f; U[i] = 0.f; Sm[i] = -1e30f; }

    const unsigned short* gkbase = bT + ((size_t)(batch * 4096 + k0)) * 256;

#define STAGE(CH, BUFHW)                                                        \
    {                                                                           \
        const unsigned short* gsp = gkbase + (size_t)(CH) * 16384 + goff;       \
        unsigned short* lp0 = kb + (BUFHW) + w * 512;                           \
        _Pragma("unroll")                                                       \
        for (int i = 0; i < 8; ++i)                                             \
            __builtin_amdgcn_global_load_lds(                                   \
                (const __attribute__((address_space(1))) void*)(gsp + i * 2048),\
                (__attribute__((address_space(3))) void*)(lp0 + i * 2048),      \
                16, 0, 0);                                                      \
    }

    STAGE(0, 0);
    __syncthreads();                     // implicit vmcnt(0): buf0 ready
    int bufOff = 0;

    for (int ch = 0; ch < 16; ++ch) {
        if (ch < 15) STAGE(ch + 1, bufOff ^ 16384);   // DMA hides under compute

#pragma unroll
        for (int nt = 0; nt < 4; ++nt) {
            f32x4 acc0 = {0.f, 0.f, 0.f, 0.f};
            f32x4 acc1 = {0.f, 0.f, 0.f, 0.f};
            const unsigned short* lp = kb + bufOff + (nt * 16 + l15) * 256;
#pragma unroll
            for (int kk = 0; kk < 8; ++kk) {
                bf16x8 bfrag = *reinterpret_cast<const bf16x8*>(lp + offs[kk]);
                acc0 = __builtin_amdgcn_mfma_f32_16x16x32_bf16(afrag[0][kk], bfrag, acc0, 0, 0, 0);
                acc1 = __builtin_amdgcn_mfma_f32_16x16x32_bf16(afrag[1][kk], bfrag, acc1, 0, 0, 0);
            }
            float kx = (float)(nt * 16 + l15);     // key & 63 (k0,ch*64 are 64-mult)
#pragma unroll
            for (int r = 0; r < 4; ++r) {
                float p0 = exp2f(acc0[r] * BETA_LOG2E);
                Z[r]  += p0;  Sx[r] += p0 * kx;
                Sm[r]  = fmaxf(Sm[r], acc0[r]);
                float p1 = exp2f(acc1[r] * BETA_LOG2E);
                Z[4 + r]  += p1;  Sx[4 + r] += p1 * kx;
                Sm[4 + r]  = fmaxf(Sm[4 + r], acc1[r]);
            }
        }
#pragma unroll
        for (int i = 0; i < 8; ++i) U[i] += Z[i];   // Abel partial for Sy
        __syncthreads();   // drains ch+1 DMA (vmcnt0) + all reads of buf done
        bufOff ^= 16384;
    }
#undef STAGE

    // reduce across the 16 col-lanes (low 4 lane bits)
#pragma unroll
    for (int i = 0; i < 8; ++i) {
#pragma unroll
        for (int m = 1; m <= 8; m <<= 1) {
            Z[i]  += __shfl_xor(Z[i], m);
            Sx[i] += __shfl_xor(Sx[i], m);
            U[i]  += __shfl_xor(U[i], m);
            Sm[i]  = fmaxf(Sm[i], __shfl_xor(Sm[i], m));
        }
    }
    if (l15 == 0) {
        float kyc = 16.0f * (float)(ks + 1);
#pragma unroll
        for (int s = 0; s < 2; ++s)
#pragma unroll
            for (int r = 0; r < 4; ++r) {
                int q = q0w + s * 16 + quad * 4 + r;   // C/D row = quad*4+reg
                int i = s * 4 + r;
                float Sy = kyc * Z[i] - U[i];          // Abel: Sy = 16(ks+1)Z - sum T_ch
                f32x4 st = {Z[i], Sx[i], Sy, exp2f(Sm[i] * BETA_LOG2E)};
                *reinterpret_cast<f32x4*>(&stats[((size_t)(batch * 4096 + q) * 4 + ks) * 4]) = st;
            }
    }
}

// ---------------------------------------------------------------------------
// Kernel 3 (round-0, passing): merge 4 key-splits, write warp then cert.
// ---------------------------------------------------------------------------
__global__ __launch_bounds__(256) void k_finalize(
    const float* __restrict__ stats, float* __restrict__ out)
{
    int q = blockIdx.x * 256 + threadIdx.x;   // [0, 16384)
    const f32x4* s = reinterpret_cast<const f32x4*>(stats + (size_t)q * 16);
    f32x4 a0 = s[0], a1 = s[1], a2 = s[2], a3 = s[3];
    float Z  = a0.x + a1.x + a2.x + a3.x;
    float Sx = a0.y + a1.y + a2.y + a3.y;
    float Sy = a0.z + a1.z + a2.z + a3.z;
    float Pm = fmaxf(fmaxf(a0.w, a1.w), fmaxf(a2.w, a3.w));
    float invZ = 1.0f / Z;
    out[q * 2 + 0]  = Sx * invZ;
    out[q * 2 + 1]  = Sy * invZ;
    out[32768 + q]  = Pm * invZ;
}

extern "C" void kernel_launch(void* const* d_in, const int* in_sizes, int n_in,
                              void* d_out, int out_size, void* d_ws, size_t ws_size,
                              hipStream_t stream)
{
    const float* f0 = (const float*)d_in[0];
    const float* f1 = (const float*)d_in[1];
    unsigned short* aT = (unsigned short*)d_ws;           // 8 MB
    unsigned short* bT = aT + (size_t)4 * 4096 * 256;     // 8 MB
    float* stats = (float*)(bT + (size_t)4 * 4096 * 256); // 16384*4*4 f32 = 1 MB
    float* out = (float*)d_out;

    hipLaunchKernelGGL(k_norm_transpose, dim3(2048), dim3(256), 0, stream, f0, f1, aT, bT);
    hipLaunchKernelGGL(k_flash,          dim3(512),  dim3(256), 0, stream, aT, bT, stats);
    hipLaunchKernelGGL(k_finalize,       dim3(64),   dim3(256), 0, stream, stats, out);
}

// Round 11
// 122.327 us; speedup vs baseline: 1.0726x; 1.0726x over previous
//
#include <hip/hip_runtime.h>
#include <hip/hip_bf16.h>

#define BETA_LOG2E 14.426950408889634f   // 10 * log2(e)
#define EPSN 1e-6f

typedef __bf16 bf16x8 __attribute__((ext_vector_type(8)));
typedef float  f32x4  __attribute__((ext_vector_type(4)));

static __device__ inline unsigned short f2bf(float f) {
    __hip_bfloat16 h = __float2bfloat16(f);
    return __builtin_bit_cast(unsigned short, h);
}
static __device__ inline float bf2f(unsigned short u) {
    unsigned int b = ((unsigned int)u) << 16;
    return __builtin_bit_cast(float, b);
}

// ---------------------------------------------------------------------------
// Kernel 1 (round-2 v3 geometry, best measured; v4's 8/CU regressed).
// L2-normalize over C, transpose [b][c][n] -> [b][n][c], bf16.
// NEW: aT (queries) is pre-scaled by BETA_LOG2E -- folds into the existing
// inv multiply, so the bf16 rounding count is IDENTICAL (error unchanged);
// removes the per-score logit multiply in flash.
// ---------------------------------------------------------------------------
__global__ __launch_bounds__(256) void k_norm_transpose(
    const float* __restrict__ f0, const float* __restrict__ f1,
    unsigned short* __restrict__ aT, unsigned short* __restrict__ bT)
{
    __shared__ unsigned short tile[32 * 256];  // [n][c] raw bf16
    __shared__ float partial[32][32];          // [cg][n]
    __shared__ float inv_l[32];

    int idx   = blockIdx.x;
    int which = idx >> 9;
    int rem   = idx & 511;
    int b     = rem >> 7;
    int n0    = (rem & 127) * 32;
    const float* src = which ? f1 : f0;
    unsigned short* dst = which ? bT : aT;
    float scale = which ? 1.0f : BETA_LOG2E;   // queries carry beta*log2(e)

    int t  = threadIdx.x;
    int nq = t & 7;     // 8 quads of 4 n  -> 32 n
    int cg = t >> 3;    // 32 groups of 8 c -> 256 c

    const float* sp = src + ((size_t)(b * 256 + cg * 8)) * 4096 + n0 + nq * 4;

    f32x4 ss = {0.f, 0.f, 0.f, 0.f};
    unsigned int pk[4][4];   // [j = n sub-row][4 uints = 8 bf16 over c]
#pragma unroll
    for (int i = 0; i < 8; ++i) {
        f32x4 v = *reinterpret_cast<const f32x4*>(sp + (size_t)i * 4096);
        ss += v * v;
#pragma unroll
        for (int j = 0; j < 4; ++j) {
            unsigned int h = f2bf(v[j]);
            if (i & 1) pk[j][i >> 1] |= h << 16;
            else       pk[j][i >> 1]  = h;
        }
    }
#pragma unroll
    for (int j = 0; j < 4; ++j) {
        int n = nq * 4 + j;
        *reinterpret_cast<uint4*>(&tile[n * 256 + cg * 8]) =
            *reinterpret_cast<const uint4*>(pk[j]);
    }
    *reinterpret_cast<f32x4*>(&partial[cg][nq * 4]) = ss;
    __syncthreads();
    if (t < 32) {
        float s = 0.f;
#pragma unroll
        for (int k = 0; k < 32; ++k) s += partial[k][t];
        inv_l[t] = scale / fmaxf(sqrtf(s), EPSN);
    }
    __syncthreads();

#pragma unroll
    for (int it = 0; it < 4; ++it) {
        int n  = it * 8 + (t >> 5);
        int cb = t & 31;
        uint4 v = *reinterpret_cast<const uint4*>(&tile[n * 256 + cb * 8]);
        float inv = inv_l[n];
        unsigned int o[4];
#pragma unroll
        for (int k = 0; k < 4; ++k) {
            unsigned int u = (&v.x)[k];
            unsigned short lo = f2bf(bf2f((unsigned short)(u & 0xffffu)) * inv);
            unsigned short hi = f2bf(bf2f((unsigned short)(u >> 16)) * inv);
            o[k] = (unsigned int)lo | ((unsigned int)hi << 16);
        }
        *reinterpret_cast<uint4*>(&dst[((size_t)(b * 4096 + n0 + n)) * 256 + cb * 8]) =
            *reinterpret_cast<const uint4*>(o);
    }
}

// ---------------------------------------------------------------------------
// Kernel 2 v12: round-10 flash (57us) + two register-neutral epilogue cuts:
//  - pre-scaled A: logits arrive as beta*log2e*cos -> no per-score mul;
//    Sm tracked in scaled units, exp2 once at writeout.
//  - Sx Abel over nt (kx = nt*16 + l15 per lane):
//      Sx = l15*Z + 48*U - 16*V,  V += Z after nt=0,1,2 each chunk,
//      U  = sum of Z after each chunk (shared with Sy = 16(ks+1)Z - U).
// Inner loop per score: exp2 + add + max (3 VALU, was 5 in round 8).
// stats[q][ks] = {Z, Sx, Sy, Pmax}
// ---------------------------------------------------------------------------
__global__ __launch_bounds__(256) void k_flash(
    const unsigned short* __restrict__ aT, const unsigned short* __restrict__ bT,
    float* __restrict__ stats)
{
    __shared__ unsigned short kb[2 * 64 * 256];   // 64 KB double-buffered

    int idx   = blockIdx.x;
    int xcd   = idx & 7;                 // XCD swizzle: batch -> 2 XCDs
    int batch = xcd >> 1;
    int sub   = ((idx >> 3) << 1) | (xcd & 1);   // [0,128)
    int qt    = sub >> 2;                // [0,32)
    int ks    = sub & 3;                 // [0,4)

    int t    = threadIdx.x;
    int w    = t >> 6;
    int lane = t & 63;
    int quad = lane >> 4;
    int l15  = lane & 15;
    int q0w  = qt * 128 + w * 32;
    int k0   = ks * 1024;

    // resident A fragments: 2 strips of 16 queries x 8 K-steps
    bf16x8 afrag[2][8];
#pragma unroll
    for (int s = 0; s < 2; ++s) {
        const unsigned short* ap =
            aT + ((size_t)(batch * 4096 + q0w + s * 16 + l15)) * 256 + quad * 8;
#pragma unroll
        for (int kk = 0; kk < 8; ++kk)
            afrag[s][kk] = *reinterpret_cast<const bf16x8*>(ap + kk * 32);
    }

    // swizzled read offsets: logical blk = quad+4kk stored at blk^(key&7),
    // key&7 == l15&7 for the rows this lane reads
    int s7 = l15 & 7;
    int offs[8];
#pragma unroll
    for (int kk = 0; kk < 8; ++kk) offs[kk] = (((quad + 4 * kk) ^ s7) << 3);

    // staging: wave w, iter i covers key = i*8 + 2w + (lane>>5), block lane&31.
    // Source pre-swizzled: block' = (lane&31) ^ (key&7); key&7 = (2w+(lane>>5))&7.
    int krem = 2 * w + (lane >> 5);
    int goff = krem * 256 + (((lane & 31) ^ (krem & 7)) << 3);

    float Z[8], V[8], U[8], Sm[8];
#pragma unroll
    for (int i = 0; i < 8; ++i) { Z[i] = 0.f; V[i] = 0.f; U[i] = 0.f; Sm[i] = -1e30f; }

    const unsigned short* gkbase = bT + ((size_t)(batch * 4096 + k0)) * 256;

#define STAGE(CH, BUFHW)                                                        \
    {                                                                           \
        const unsigned short* gsp = gkbase + (size_t)(CH) * 16384 + goff;       \
        unsigned short* lp0 = kb + (BUFHW) + w * 512;                           \
        _Pragma("unroll")                                                       \
        for (int i = 0; i < 8; ++i)                                             \
            __builtin_amdgcn_global_load_lds(                                   \
                (const __attribute__((address_space(1))) void*)(gsp + i * 2048),\
                (__attribute__((address_space(3))) void*)(lp0 + i * 2048),      \
                16, 0, 0);                                                      \
    }

    STAGE(0, 0);
    __syncthreads();                     // implicit vmcnt(0): buf0 ready
    int bufOff = 0;

    for (int ch = 0; ch < 16; ++ch) {
        if (ch < 15) STAGE(ch + 1, bufOff ^ 16384);   // DMA hides under compute

#pragma unroll
        for (int nt = 0; nt < 4; ++nt) {
            f32x4 acc0 = {0.f, 0.f, 0.f, 0.f};
            f32x4 acc1 = {0.f, 0.f, 0.f, 0.f};
            const unsigned short* lp = kb + bufOff + (nt * 16 + l15) * 256;
#pragma unroll
            for (int kk = 0; kk < 8; ++kk) {
                bf16x8 bfrag = *reinterpret_cast<const bf16x8*>(lp + offs[kk]);
                acc0 = __builtin_amdgcn_mfma_f32_16x16x32_bf16(afrag[0][kk], bfrag, acc0, 0, 0, 0);
                acc1 = __builtin_amdgcn_mfma_f32_16x16x32_bf16(afrag[1][kk], bfrag, acc1, 0, 0, 0);
            }
            // acc is already beta*log2e*cos (A pre-scaled): 3 VALU per score
#pragma unroll
            for (int r = 0; r < 4; ++r) {
                float p0 = exp2f(acc0[r]);
                Z[r]  += p0;
                Sm[r]  = fmaxf(Sm[r], acc0[r]);
                float p1 = exp2f(acc1[r]);
                Z[4 + r]  += p1;
                Sm[4 + r]  = fmaxf(Sm[4 + r], acc1[r]);
            }
            if (nt < 3) {
#pragma unroll
                for (int i = 0; i < 8; ++i) V[i] += Z[i];   // Abel partials for Sx
            }
        }
#pragma unroll
        for (int i = 0; i < 8; ++i) U[i] += Z[i];           // Abel partials for Sy
        __syncthreads();   // drains ch+1 DMA (vmcnt0) + all reads of buf done
        bufOff ^= 16384;
    }
#undef STAGE

    // per-lane Sx prefix (l15-weighted term must precede the lane reduce)
    float l15f = (float)l15;
#pragma unroll
    for (int i = 0; i < 8; ++i) V[i] = l15f * Z[i] - 16.0f * V[i];   // S0

    // reduce across the 16 col-lanes (low 4 lane bits)
#pragma unroll
    for (int i = 0; i < 8; ++i) {
#pragma unroll
        for (int m = 1; m <= 8; m <<= 1) {
            Z[i]  += __shfl_xor(Z[i], m);
            V[i]  += __shfl_xor(V[i], m);
            U[i]  += __shfl_xor(U[i], m);
            Sm[i]  = fmaxf(Sm[i], __shfl_xor(Sm[i], m));
        }
    }
    if (l15 == 0) {
        float kyc = 16.0f * (float)(ks + 1);
#pragma unroll
        for (int s = 0; s < 2; ++s)
#pragma unroll
            for (int r = 0; r < 4; ++r) {
                int q = q0w + s * 16 + quad * 4 + r;   // C/D row = quad*4+reg
                int i = s * 4 + r;
                float Sx = V[i] + 48.0f * U[i];        // S0 + 48U
                float Sy = kyc * Z[i] - U[i];          // 16(ks+1)Z - U
                f32x4 st = {Z[i], Sx, Sy, exp2f(Sm[i])};
                *reinterpret_cast<f32x4*>(&stats[((size_t)(batch * 4096 + q) * 4 + ks) * 4]) = st;
            }
    }
}

// ---------------------------------------------------------------------------
// Kernel 3 (round-0, passing): merge 4 key-splits, write warp then cert.
// ---------------------------------------------------------------------------
__global__ __launch_bounds__(256) void k_finalize(
    const float* __restrict__ stats, float* __restrict__ out)
{
    int q = blockIdx.x * 256 + threadIdx.x;   // [0, 16384)
    const f32x4* s = reinterpret_cast<const f32x4*>(stats + (size_t)q * 16);
    f32x4 a0 = s[0], a1 = s[1], a2 = s[2], a3 = s[3];
    float Z  = a0.x + a1.x + a2.x + a3.x;
    float Sx = a0.y + a1.y + a2.y + a3.y;
    float Sy = a0.z + a1.z + a2.z + a3.z;
    float Pm = fmaxf(fmaxf(a0.w, a1.w), fmaxf(a2.w, a3.w));
    float invZ = 1.0f / Z;
    out[q * 2 + 0]  = Sx * invZ;
    out[q * 2 + 1]  = Sy * invZ;
    out[32768 + q]  = Pm * invZ;
}

extern "C" void kernel_launch(void* const* d_in, const int* in_sizes, int n_in,
                              void* d_out, int out_size, void* d_ws, size_t ws_size,
                              hipStream_t stream)
{
    const float* f0 = (const float*)d_in[0];
    const float* f1 = (const float*)d_in[1];
    unsigned short* aT = (unsigned short*)d_ws;           // 8 MB
    unsigned short* bT = aT + (size_t)4 * 4096 * 256;     // 8 MB
    float* stats = (float*)(bT + (size_t)4 * 4096 * 256); // 16384*4*4 f32 = 1 MB
    float* out = (float*)d_out;

    hipLaunchKernelGGL(k_norm_transpose, dim3(1024), dim3(256), 0, stream, f0, f1, aT, bT);
    hipLaunchKernelGGL(k_flash,          dim3(512),  dim3(256), 0, stream, aT, bT, stats);
    hipLaunchKernelGGL(k_finalize,       dim3(64),   dim3(256), 0, stream, stats, out);
}